// Round 2
// baseline (33.117 us; speedup 1.0000x reference)
//
#include <hip/hip_runtime.h>
#include <math.h>

#define NB 256          // batch
#define NT 4            // task dim
#define NTL 65536       // T*L flattened per sample
#define CHUNKS 8        // blocks per sample
#define CHUNK_ELEMS (NTL / CHUNKS)   // 8192
#define BLOCK 256
#define K_ITERS (CHUNK_ELEMS / 4 / BLOCK)  // 8 float4 iters/thread

// lgamma(x+1) for non-negative integer-valued x (data is 0..4); general fallback.
__device__ __forceinline__ float lgfact(float x) {
  if (x < 1.5f) return 0.0f;                       // 0!, 1!
  if (x < 2.5f) return 0.69314718055994531f;       // ln 2
  if (x < 3.5f) return 1.79175946922805500f;       // ln 6
  if (x < 4.5f) return 3.17805383034794562f;       // ln 24
  if (x < 5.5f) return 4.78749174278204599f;       // ln 120
  if (x < 6.5f) return 6.57925121201010100f;       // ln 720
  if (x < 7.5f) return 8.52516136106541430f;       // ln 5040
  return lgammaf(x + 1.0f);
}

__global__ __launch_bounds__(BLOCK) void nll_partials(
    const float* __restrict__ logits,
    const float* __restrict__ xcnt,
    float* __restrict__ ws)
{
  const int blk = blockIdx.x;
  const int b = blk / CHUNKS;
  const int c = blk % CHUNKS;
  const int t = threadIdx.x;
  const size_t base = (size_t)b * NTL + (size_t)c * CHUNK_ELEMS;
  const float4* __restrict__ l4 = (const float4*)(logits + base);
  const float4* __restrict__ x4 = (const float4*)(xcnt + base);

  // ---- issue all logit loads up front (8 independent dwordx4) ----
  float4 l[K_ITERS];
#pragma unroll
  for (int k = 0; k < K_ITERS; ++k) l[k] = l4[t + k * BLOCK];

  // ---- stream x: dot / sum(x) / sum(lgamma(x+1)) with rotating accumulators ----
  float dot0 = 0.f, dot1 = 0.f, dot2 = 0.f, dot3 = 0.f;
  float sx0 = 0.f, sx1 = 0.f;
  float slg0 = 0.f, slg1 = 0.f;
#pragma unroll
  for (int k = 0; k < K_ITERS; ++k) {
    const float4 x = x4[t + k * BLOCK];
    dot0 = fmaf(x.x, l[k].x, dot0);
    dot1 = fmaf(x.y, l[k].y, dot1);
    dot2 = fmaf(x.z, l[k].z, dot2);
    dot3 = fmaf(x.w, l[k].w, dot3);
    sx0 += (x.x + x.y);
    sx1 += (x.z + x.w);
    slg0 += (lgfact(x.x) + lgfact(x.y));
    slg1 += (lgfact(x.z) + lgfact(x.w));
  }
  float dot = (dot0 + dot1) + (dot2 + dot3);
  float sx = sx0 + sx1;
  float slg = slg0 + slg1;

  // ---- per-thread max (full-rate fmax tree over held registers) ----
  float m0 = fmaxf(fmaxf(l[0].x, l[0].y), fmaxf(l[0].z, l[0].w));
  float m1 = fmaxf(fmaxf(l[1].x, l[1].y), fmaxf(l[1].z, l[1].w));
  float m2 = fmaxf(fmaxf(l[2].x, l[2].y), fmaxf(l[2].z, l[2].w));
  float m3 = fmaxf(fmaxf(l[3].x, l[3].y), fmaxf(l[3].z, l[3].w));
  float m4 = fmaxf(fmaxf(l[4].x, l[4].y), fmaxf(l[4].z, l[4].w));
  float m5 = fmaxf(fmaxf(l[5].x, l[5].y), fmaxf(l[5].z, l[5].w));
  float m6 = fmaxf(fmaxf(l[6].x, l[6].y), fmaxf(l[6].z, l[6].w));
  float m7 = fmaxf(fmaxf(l[7].x, l[7].y), fmaxf(l[7].z, l[7].w));
  float m = fmaxf(fmaxf(fmaxf(m0, m1), fmaxf(m2, m3)),
                  fmaxf(fmaxf(m4, m5), fmaxf(m6, m7)));

  // ---- single exp pass, 4 independent accumulators ----
  float s0 = 0.f, s1 = 0.f, s2 = 0.f, s3 = 0.f;
#pragma unroll
  for (int k = 0; k < K_ITERS; ++k) {
    s0 += __expf(l[k].x - m);
    s1 += __expf(l[k].y - m);
    s2 += __expf(l[k].z - m);
    s3 += __expf(l[k].w - m);
  }
  float s = (s0 + s1) + (s2 + s3);

  // ---- 64-lane butterfly reduce ----
#pragma unroll
  for (int off = 32; off >= 1; off >>= 1) {
    const float m2_ = __shfl_xor(m, off);
    const float s2_ = __shfl_xor(s, off);
    const float nm = fmaxf(m, m2_);
    s = s * __expf(m - nm) + s2_ * __expf(m2_ - nm);
    m = nm;
    dot += __shfl_xor(dot, off);
    sx  += __shfl_xor(sx,  off);
    slg += __shfl_xor(slg, off);
  }

  __shared__ float sm[4], ss[4], sdot[4], ssx[4], sslg[4];
  const int wid = t >> 6;
  if ((t & 63) == 0) { sm[wid] = m; ss[wid] = s; sdot[wid] = dot; ssx[wid] = sx; sslg[wid] = slg; }
  __syncthreads();
  if (t == 0) {
    float M = sm[0], S = ss[0], D = sdot[0], X = ssx[0], G = sslg[0];
#pragma unroll
    for (int w = 1; w < BLOCK / 64; ++w) {
      const float nm = fmaxf(M, sm[w]);
      S = S * __expf(M - nm) + ss[w] * __expf(sm[w] - nm);
      M = nm;
      D += sdot[w]; X += ssx[w]; G += sslg[w];
    }
    float* p = ws + (size_t)blk * 5;
    p[0] = M; p[1] = S; p[2] = D; p[3] = X; p[4] = G;
  }
}

__global__ __launch_bounds__(NB) void finalize(
    const float* __restrict__ pred_counts,
    const float* __restrict__ target_counts,
    const float* __restrict__ cw,
    const float* __restrict__ ws,
    float* __restrict__ out)
{
  const int b = threadIdx.x;  // one thread per sample

  float m = -INFINITY, s = 0.f, dot = 0.f, sx = 0.f, slg = 0.f;
#pragma unroll
  for (int c = 0; c < CHUNKS; ++c) {
    const float* p = ws + (size_t)(b * CHUNKS + c) * 5;
    const float m2 = p[0], s2 = p[1];
    const float nm = fmaxf(m, m2);
    s = s * __expf(m - nm) + s2 * __expf(m2 - nm);
    m = nm;
    dot += p[2]; sx += p[3]; slg += p[4];
  }
  const float n = sx;
  const float lse = m + logf(s);
  const float log_prob = lgammaf(n + 1.0f) - slg + dot - n * lse;

  float tt = 0.f, tp = 0.f;
#pragma unroll
  for (int j = 0; j < NT; ++j) {
    tt += target_counts[b * NT + j];
    tp += pred_counts[b * NT + j];
  }
  const float d = tt - tp;
  const float val = -log_prob + cw[0] * d * d;

  __shared__ float red[NB];
  red[b] = val;
  __syncthreads();
#pragma unroll
  for (int off = NB / 2; off >= 1; off >>= 1) {
    if (b < off) red[b] += red[b + off];
    __syncthreads();
  }
  if (b == 0) out[0] = red[0] * (1.0f / NB);
}

extern "C" void kernel_launch(void* const* d_in, const int* in_sizes, int n_in,
                              void* d_out, int out_size, void* d_ws, size_t ws_size,
                              hipStream_t stream) {
  const float* pred_counts   = (const float*)d_in[0];
  const float* target_counts = (const float*)d_in[1];
  const float* pred_prof     = (const float*)d_in[2];
  const float* target_prof   = (const float*)d_in[3];
  const float* cw            = (const float*)d_in[4];
  float* out = (float*)d_out;
  float* ws  = (float*)d_ws;   // needs NB*CHUNKS*5 floats = 40 KiB

  nll_partials<<<NB * CHUNKS, BLOCK, 0, stream>>>(pred_prof, target_prof, ws);
  finalize<<<1, NB, 0, stream>>>(pred_counts, target_counts, cw, ws, out);
}